// Round 3
// baseline (372.689 us; speedup 1.0000x reference)
//
#include <hip/hip_runtime.h>
#include <hip/hip_bf16.h>
#include <stdint.h>

// ---------------------------------------------------------------------------
// MHA forward, bf16 MFMA path (gfx950).  B=1, S=4096, D=1024, H=16, HD=64.
//   1. preprocess: cast x->bf16 + transpose-cast Wq|Wk|Wv, Wo
//   2. gemm_qkv: QK = xb @ Wt^T (stride 2048, Q pre-scaled 0.125*log2e);
//      V scatter-stored transposed to Vt[1024][4096]
//   3. flash_attn: ROUND-12. Evidence so far:
//        R0 (64q waves): 192 regs -> 2/SIMD cap, occ 19.5%, 75 us.
//        R2 (32q waves): 112 regs (VGPR_Count=80 measured) -> 4/SIMD capable,
//          but 1024-block grid = fully co-resident -> NO backfill; causal
//          imbalance (T=1..64) decayed time-avg occ to 27% (= avg/max*50%),
//          plus just-in-time V load serialized L2 latency -> 140 us.
//      Fix: R0's inner loop (K AND V ping-pong, barrier-free waves) at R2's
//      register footprint, with 2x block oversubscription for backfill:
//      2048 blocks (128 qb x 16 heads), block = 32q x 128k tile, 4 key-split
//      waves (32k each), T = qb/4+1, LPT (qb=127 first), XCD-local heads,
//      dead-wave early exit (wave w>qb%4 skips last tile), setprio around
//      compute. __launch_bounds__(256,4): cap 128 combined ~= need (~96+32).
//   4. gemm_out: out = Ctx @ Wot^T + bo (fp32), 64x128 tiles (512 blocks)
// ---------------------------------------------------------------------------

typedef __bf16 bf16;
typedef __bf16 bf16x4 __attribute__((ext_vector_type(4)));
typedef __bf16 bf16x8 __attribute__((ext_vector_type(8)));
typedef float  f32x4  __attribute__((ext_vector_type(4)));

#define MFMA32(a, b, c) __builtin_amdgcn_mfma_f32_16x16x32_bf16((a), (b), (c), 0, 0, 0)

static constexpr int S_LEN  = 4096;
static constexpr int DMODEL = 1024;
static constexpr int HDIM   = 64;
static constexpr int LDQK   = 2048;

#define GLOAD_LDS16(g, l)                                                      \
  __builtin_amdgcn_global_load_lds((__attribute__((address_space(1))) void*)(g), \
                                   (__attribute__((address_space(3))) void*)(l), 16, 0, 0)

// ------------- fused preprocess: cast x + 4 weight transposes --------------
__global__ __launch_bounds__(256) void preprocess(const float* __restrict__ x,
                                                  const float* __restrict__ Wq,
                                                  const float* __restrict__ Wk,
                                                  const float* __restrict__ Wv,
                                                  const float* __restrict__ Wo,
                                                  bf16* __restrict__ xb,
                                                  bf16* __restrict__ Wt,
                                                  bf16* __restrict__ Wot) {
  __shared__ float tile[64][65];
  const int t = threadIdx.x, b = blockIdx.x;
  if (b < 1024) {
#pragma unroll
    for (int i = 0; i < 4; i++) {
      int idx = b * 1024 + i * 256 + t;
      float4 v = ((const float4*)x)[idx];
      bf16x4 o;
      o[0] = (bf16)v.x; o[1] = (bf16)v.y; o[2] = (bf16)v.z; o[3] = (bf16)v.w;
      ((bf16x4*)xb)[idx] = o;
    }
    return;
  }
  const int id = b - 1024;
  const int wsel = id >> 8;
  const int t2 = id & 255;
  const int kb = (t2 & 15) * 64, nb = (t2 >> 4) * 64;
  const float* src = (wsel == 0) ? Wq : (wsel == 1) ? Wk : (wsel == 2) ? Wv : Wo;
  bf16* dst = (wsel < 3) ? (Wt + (size_t)wsel * 1024 * 1024) : Wot;
#pragma unroll
  for (int i = 0; i < 16; i++) {
    int idx = t + i * 256;
    int r = idx >> 6, c = idx & 63;
    tile[r][c] = src[(size_t)(kb + r) * 1024 + nb + c];
  }
  __syncthreads();
#pragma unroll
  for (int i = 0; i < 16; i++) {
    int idx = t + i * 256;
    int cc = idx >> 6, rr = idx & 63;
    dst[(size_t)(nb + cc) * 1024 + kb + rr] = (bf16)tile[rr][cc];
  }
}

// ------------------- gemm_qkv: 128x128 tile, K=1024, BK=32 -----------------
__global__ __launch_bounds__(256) void gemm_qkv(const bf16* __restrict__ A,
                                                const bf16* __restrict__ Bt,
                                                bf16* __restrict__ QK,
                                                bf16* __restrict__ Vt) {
  __shared__ bf16 lsA[128 * 32];
  __shared__ bf16 lsB[128 * 32];
  const int tid = threadIdx.x, w = tid >> 6, lane = tid & 63;
  const int l15 = lane & 15, quad = lane >> 4;
  const int m0 = blockIdx.x * 128, n0 = blockIdx.y * 128;
  const int wm = (w >> 1) * 64, wn = (w & 1) * 64;
  const int rowA = lane >> 2;
  const int colk = (lane & 3) * 8;

  f32x4 acc[4][4] = {};

  for (int k0 = 0; k0 < 1024; k0 += 32) {
    __syncthreads();
#pragma unroll
    for (int i = 0; i < 2; i++) {
      int s = w * 2 + i;
      const bf16* ga = A + (size_t)(m0 + s * 16 + rowA) * 1024 + k0 + colk;
      GLOAD_LDS16(ga, lsA + s * 512);
      const bf16* gb = Bt + (size_t)(n0 + s * 16 + rowA) * 1024 + k0 + colk;
      GLOAD_LDS16(gb, lsB + s * 512);
    }
    __syncthreads();

    bf16x8 af[4], bfr[4];
#pragma unroll
    for (int r = 0; r < 4; r++)
      af[r] = *(const bf16x8*)(lsA + (wm + r * 16 + l15) * 32 + quad * 8);
#pragma unroll
    for (int c = 0; c < 4; c++)
      bfr[c] = *(const bf16x8*)(lsB + (wn + c * 16 + l15) * 32 + quad * 8);
#pragma unroll
    for (int r = 0; r < 4; r++)
#pragma unroll
      for (int c = 0; c < 4; c++)
        acc[r][c] = MFMA32(af[r], bfr[c], acc[r][c]);
  }

  if (n0 < 2048) {
#pragma unroll
    for (int r = 0; r < 4; r++) {
#pragma unroll
      for (int c = 0; c < 4; c++) {
        int col = n0 + wn + c * 16 + l15;
        float scale = (col < 1024) ? 0.18033688f : 1.0f;  // 0.125*log2e on Q
#pragma unroll
        for (int e = 0; e < 4; e++) {
          int row = m0 + wm + r * 16 + quad * 4 + e;
          QK[(size_t)row * LDQK + col] = (bf16)(acc[r][c][e] * scale);
        }
      }
    }
  } else {
#pragma unroll
    for (int r = 0; r < 4; r++) {
#pragma unroll
      for (int c = 0; c < 4; c++) {
        int vcol = (n0 - 2048) + wn + c * 16 + l15;
        int row0 = m0 + wm + r * 16 + quad * 4;
        bf16x4 pk;
#pragma unroll
        for (int e = 0; e < 4; e++) pk[e] = (bf16)acc[r][c][e];
        *(bf16x4*)(Vt + (size_t)vcol * S_LEN + row0) = pk;
      }
    }
  }
}

// ----------------------------- flash attention -----------------------------
// 2048 blocks x 256 thr (4 waves). Block i: head=(i&7)+8*((i>>3)&1)
// (XCD-local heads), qb = 127-(i>>4) (LPT; 2x oversubscription -> backfill).
// Block = 32 q-rows [qb*32, +32), 128-key tiles, wave w owns keys w*32..+32
// of each tile. T = qb/4+1. Wave w with w > qb%4 is fully masked on the last
// tile and exits one tile early (no barriers in main loop).
__global__ __launch_bounds__(256, 4) void flash_attn(const bf16* __restrict__ QK,
                                                     const bf16* __restrict__ Vt,
                                                     bf16* __restrict__ Ctx) {
  __shared__ float Obuf[4][16][68];   // 17.4 KB: per-wave partial O, 16-row chunk
  __shared__ float Lbuf[4][4][32];    // 2 KB
  const int tid = threadIdx.x, w = tid >> 6, lane = tid & 63;
  const int l15 = lane & 15, quad = lane >> 4;
  const int i = blockIdx.x;
  const int head = (i & 7) + 8 * ((i >> 3) & 1);
  const int qb = 127 - (i >> 4);                             // 0..127
  const int hq = head * HDIM;
  const int q0 = qb * 32;
  const int krow0 = w * 32 + ((l15 >> 2) << 3) + (l15 & 3);  // permuted key row
  const int T = (qb >> 2) + 1;                               // 128-key tiles
  // last tile keys for wave w start at (qb/4)*128 + 32w; all-masked iff w > qb%4
  const int Tw = T - ((w > (qb & 3)) ? 1 : 0);

  // Q frags (B-operand): q = q0 + qg*16 + l15, d = kk*32 + quad*8 + j
  bf16x8 qf[2][2];
#pragma unroll
  for (int qg = 0; qg < 2; qg++)
#pragma unroll
    for (int kk = 0; kk < 2; kk++)
      qf[qg][kk] = *(const bf16x8*)(QK + (size_t)(q0 + qg * 16 + l15) * LDQK +
                                    hq + kk * 32 + quad * 8);

  f32x4 oacc[2][4] = {};
  float lsum[2] = {0.f, 0.f};

  auto load_k = [&](int j, bf16x8 (&kf)[2][2]) {
#pragma unroll
    for (int c = 0; c < 2; c++)
#pragma unroll
      for (int kk = 0; kk < 2; kk++)
        kf[c][kk] = *(const bf16x8*)(QK + (size_t)(j * 128 + krow0 + 4 * c) * LDQK +
                                     DMODEL + hq + kk * 32 + quad * 8);
  };
  auto load_v = [&](int j, bf16x8 (&vf)[4]) {
#pragma unroll
    for (int dg = 0; dg < 4; dg++)
      vf[dg] = *(const bf16x8*)(Vt + (size_t)(hq + dg * 16 + l15) * S_LEN +
                                j * 128 + w * 32 + quad * 8);
  };
  auto compute = [&](int j, bf16x8 (&kf)[2][2], bf16x8 (&vf)[4]) {
    __builtin_amdgcn_s_setprio(1);
    // S^T = K Q^T : C row = key-slot quad*4+e (c group), col = q = l15
    f32x4 sacc[2][2] = {};
#pragma unroll
    for (int kk = 0; kk < 2; kk++)
#pragma unroll
      for (int c = 0; c < 2; c++)
#pragma unroll
        for (int qg = 0; qg < 2; qg++)
          sacc[c][qg] = MFMA32(kf[c][kk], qf[qg][kk], sacc[c][qg]);

    bf16x8 pfr[2];
    if (j == T - 1) {
      const int kb0 = j * 128 + w * 32 + quad * 8;   // + 4c + e = actual key
#pragma unroll
      for (int qg = 0; qg < 2; qg++) {
        const int qrow = q0 + qg * 16 + l15;
        bf16x8 pb;
#pragma unroll
        for (int c = 0; c < 2; c++)
#pragma unroll
          for (int e = 0; e < 4; e++) {
            float s = sacc[c][qg][e];
            if (kb0 + 4 * c + e > qrow) s = -1e30f;
            float pv = __builtin_amdgcn_exp2f(s);
            lsum[qg] += pv;
            pb[c * 4 + e] = (bf16)pv;
          }
        pfr[qg] = pb;
      }
    } else {
#pragma unroll
      for (int qg = 0; qg < 2; qg++) {
        bf16x8 pb;
#pragma unroll
        for (int c = 0; c < 2; c++)
#pragma unroll
          for (int e = 0; e < 4; e++) {
            float pv = __builtin_amdgcn_exp2f(sacc[c][qg][e]);
            lsum[qg] += pv;
            pb[c * 4 + e] = (bf16)pv;
          }
        pfr[qg] = pb;
      }
    }

    // O += P V  (K=32, P direct from registers)
#pragma unroll
    for (int qg = 0; qg < 2; qg++)
#pragma unroll
      for (int dg = 0; dg < 4; dg++)
        oacc[qg][dg] = MFMA32(pfr[qg], vf[dg], oacc[qg][dg]);
    __builtin_amdgcn_s_setprio(0);
  };

  // K and V both ping-ponged one tile ahead (R0 pattern).
  bf16x8 kfA[2][2], kfB[2][2], vfA[4], vfB[4];
  if (Tw > 0) {
    load_k(0, kfA); load_v(0, vfA);
    for (int j = 0; j < Tw; j += 2) {
      if (j + 1 < Tw) { load_k(j + 1, kfB); load_v(j + 1, vfB); }
      compute(j, kfA, vfA);
      if (j + 2 < Tw) { load_k(j + 2, kfA); load_v(j + 2, vfA); }
      if (j + 1 < Tw) compute(j + 1, kfB, vfB);
    }
  }

  // ---- cross-wave reduction: all 4 key-split waves share the same 32 rows ----
#pragma unroll
  for (int qg = 0; qg < 2; qg++)
    Lbuf[w][quad][qg * 16 + l15] = lsum[qg];

  const int row = tid >> 4;               // 0..15 (q within 16-row chunk)
  const int col = (tid & 15) * 4;         // 0..60 (d within head)
  for (int cp = 0; cp < 2; cp++) {        // chunk = qg index
#pragma unroll
    for (int dg = 0; dg < 4; dg++)
#pragma unroll
      for (int e = 0; e < 4; e++)
        Obuf[w][quad * 4 + e][dg * 16 + l15] = oacc[cp][dg][e];
    __syncthreads();                      // writes visible (covers Lbuf too)
    f32x4 os = {};
#pragma unroll
    for (int ww = 0; ww < 4; ww++)
      os += *(const f32x4*)&Obuf[ww][row][col];
    float lr = 0.f;
#pragma unroll
    for (int ww = 0; ww < 4; ww++)
#pragma unroll
      for (int qq = 0; qq < 4; qq++)
        lr += Lbuf[ww][qq][cp * 16 + row];
    const float linv = 1.f / lr;
    bf16x4 ob;
#pragma unroll
    for (int e2 = 0; e2 < 4; e2++) ob[e2] = (bf16)(os[e2] * linv);
    *(bf16x4*)(Ctx + (size_t)(q0 + cp * 16 + row) * DMODEL + hq + col) = ob;
    __syncthreads();                      // reads done before next chunk
  }
}

// ---------------- gemm_out: 64x128 tile, K=1024 -> 512 blocks --------------
__global__ __launch_bounds__(256) void gemm_out(const bf16* __restrict__ A,
                                                const bf16* __restrict__ Bt,
                                                float* __restrict__ C,
                                                const float* __restrict__ bias) {
  __shared__ bf16 lsA[64 * 32];
  __shared__ bf16 lsB[128 * 32];
  const int tid = threadIdx.x, w = tid >> 6, lane = tid & 63;
  const int l15 = lane & 15, quad = lane >> 4;
  const int m0 = blockIdx.x * 64, n0 = blockIdx.y * 128;
  const int wm = (w >> 1) * 32, wn = (w & 1) * 64;
  const int rowA = lane >> 2;
  const int colk = (lane & 3) * 8;

  f32x4 acc[2][4] = {};

  for (int k0 = 0; k0 < 1024; k0 += 32) {
    __syncthreads();
#pragma unroll
    for (int i = 0; i < 3; i++) {
      int s = w * 3 + i;
      if (s < 4) {
        const bf16* ga = A + (size_t)(m0 + s * 16 + rowA) * 1024 + k0 + colk;
        GLOAD_LDS16(ga, lsA + s * 512);
      } else {
        const bf16* gb = Bt + (size_t)(n0 + (s - 4) * 16 + rowA) * 1024 + k0 + colk;
        GLOAD_LDS16(gb, lsB + (s - 4) * 512);
      }
    }
    __syncthreads();

    bf16x8 af[2], bfr[4];
#pragma unroll
    for (int r = 0; r < 2; r++)
      af[r] = *(const bf16x8*)(lsA + (wm + r * 16 + l15) * 32 + quad * 8);
#pragma unroll
    for (int c = 0; c < 4; c++)
      bfr[c] = *(const bf16x8*)(lsB + (wn + c * 16 + l15) * 32 + quad * 8);
#pragma unroll
    for (int r = 0; r < 2; r++)
#pragma unroll
      for (int c = 0; c < 4; c++)
        acc[r][c] = MFMA32(af[r], bfr[c], acc[r][c]);
  }

#pragma unroll
  for (int r = 0; r < 2; r++) {
#pragma unroll
    for (int c = 0; c < 4; c++) {
      int col = n0 + wn + c * 16 + l15;
#pragma unroll
      for (int e = 0; e < 4; e++) {
        int row = m0 + wm + r * 16 + quad * 4 + e;
        C[(size_t)row * 1024 + col] = acc[r][c][e] + bias[col];
      }
    }
  }
}

// ------------------------------- launcher ----------------------------------
extern "C" void kernel_launch(void* const* d_in, const int* in_sizes, int n_in,
                              void* d_out, int out_size, void* d_ws, size_t ws_size,
                              hipStream_t stream) {
  const float* x  = (const float*)d_in[0];
  const float* Wq = (const float*)d_in[1];
  const float* Wk = (const float*)d_in[2];
  const float* Wv = (const float*)d_in[3];
  const float* Wo = (const float*)d_in[4];
  const float* bo = (const float*)d_in[5];

  char* ws = (char*)d_ws;                    // 48 MB total
  bf16* xb  = (bf16*)(ws);                   // 8 MB  [4096][1024]
  bf16* Wt  = (bf16*)(ws + (8u  << 20));     // 6 MB  [3072][1024]
  bf16* Wot = (bf16*)(ws + (14u << 20));     // 2 MB  [1024][1024]
  bf16* QK  = (bf16*)(ws + (16u << 20));     // 16 MB [4096][2048]
  bf16* Vt  = (bf16*)(ws + (32u << 20));     // 8 MB  [1024][4096]
  bf16* Ctx = (bf16*)(ws + (40u << 20));     // 8 MB  [4096][1024]

  preprocess<<<2048, 256, 0, stream>>>(x, Wq, Wk, Wv, Wo, xb, Wt, Wot);
  gemm_qkv<<<dim3(32, 24), 256, 0, stream>>>(xb, Wt, QK, Vt);
  flash_attn<<<2048, 256, 0, stream>>>(QK, Vt, Ctx);
  gemm_out<<<dim3(64, 8), 256, 0, stream>>>(Ctx, Wot, (float*)d_out, bo);
}

// Round 4
// 260.268 us; speedup vs baseline: 1.4319x; 1.4319x over previous
//
#include <hip/hip_runtime.h>
#include <hip/hip_bf16.h>
#include <stdint.h>

// ---------------------------------------------------------------------------
// MHA forward, bf16 MFMA path (gfx950).  B=1, S=4096, D=1024, H=16, HD=64.
//   1. preprocess: cast x->bf16 + transpose-cast Wq|Wk|Wv, Wo
//   2. gemm_qkv: QK = xb @ Wt^T (stride 2048, Q pre-scaled 0.125*log2e);
//      V scatter-stored transposed to Vt[1024][4096]
//   3. flash_attn: ROUND-13. Ledger:
//        R0 (64q waves, K+V pingpong):   192 regs, 2/SIMD, occ 19.5%, 75 us
//        R2 (32q, V just-in-time):       112 regs, occ 27% (no backfill), 140 us
//        R3 (32q, K+V pingpong, FORCED (256,4)): cap 128 < need ~144 ->
//            506 MB scratch writes, 256 us. BUT occupancy hit 42% -> the
//            2048-block oversubscription + LPT + key-split structure works.
//      Fix: identical structure, (256,3): cap 170 > need ~144 -> no spill,
//      3 blocks/CU, 12 waves/CU (37.5% ceiling). 2048 blocks (128 qb x 16
//      heads), block = 32q x 128k tile, 4 key-split waves, T = qb/4+1,
//      LPT (qb=127 first), XCD-local heads, dead-wave early exit, setprio.
//   4. gemm_out: out = Ctx @ Wot^T + bo (fp32), 64x128 tiles (512 blocks)
// ---------------------------------------------------------------------------

typedef __bf16 bf16;
typedef __bf16 bf16x4 __attribute__((ext_vector_type(4)));
typedef __bf16 bf16x8 __attribute__((ext_vector_type(8)));
typedef float  f32x4  __attribute__((ext_vector_type(4)));

#define MFMA32(a, b, c) __builtin_amdgcn_mfma_f32_16x16x32_bf16((a), (b), (c), 0, 0, 0)

static constexpr int S_LEN  = 4096;
static constexpr int DMODEL = 1024;
static constexpr int HDIM   = 64;
static constexpr int LDQK   = 2048;

#define GLOAD_LDS16(g, l)                                                      \
  __builtin_amdgcn_global_load_lds((__attribute__((address_space(1))) void*)(g), \
                                   (__attribute__((address_space(3))) void*)(l), 16, 0, 0)

// ------------- fused preprocess: cast x + 4 weight transposes --------------
__global__ __launch_bounds__(256) void preprocess(const float* __restrict__ x,
                                                  const float* __restrict__ Wq,
                                                  const float* __restrict__ Wk,
                                                  const float* __restrict__ Wv,
                                                  const float* __restrict__ Wo,
                                                  bf16* __restrict__ xb,
                                                  bf16* __restrict__ Wt,
                                                  bf16* __restrict__ Wot) {
  __shared__ float tile[64][65];
  const int t = threadIdx.x, b = blockIdx.x;
  if (b < 1024) {
#pragma unroll
    for (int i = 0; i < 4; i++) {
      int idx = b * 1024 + i * 256 + t;
      float4 v = ((const float4*)x)[idx];
      bf16x4 o;
      o[0] = (bf16)v.x; o[1] = (bf16)v.y; o[2] = (bf16)v.z; o[3] = (bf16)v.w;
      ((bf16x4*)xb)[idx] = o;
    }
    return;
  }
  const int id = b - 1024;
  const int wsel = id >> 8;
  const int t2 = id & 255;
  const int kb = (t2 & 15) * 64, nb = (t2 >> 4) * 64;
  const float* src = (wsel == 0) ? Wq : (wsel == 1) ? Wk : (wsel == 2) ? Wv : Wo;
  bf16* dst = (wsel < 3) ? (Wt + (size_t)wsel * 1024 * 1024) : Wot;
#pragma unroll
  for (int i = 0; i < 16; i++) {
    int idx = t + i * 256;
    int r = idx >> 6, c = idx & 63;
    tile[r][c] = src[(size_t)(kb + r) * 1024 + nb + c];
  }
  __syncthreads();
#pragma unroll
  for (int i = 0; i < 16; i++) {
    int idx = t + i * 256;
    int cc = idx >> 6, rr = idx & 63;
    dst[(size_t)(nb + cc) * 1024 + kb + rr] = (bf16)tile[rr][cc];
  }
}

// ------------------- gemm_qkv: 128x128 tile, K=1024, BK=32 -----------------
__global__ __launch_bounds__(256) void gemm_qkv(const bf16* __restrict__ A,
                                                const bf16* __restrict__ Bt,
                                                bf16* __restrict__ QK,
                                                bf16* __restrict__ Vt) {
  __shared__ bf16 lsA[128 * 32];
  __shared__ bf16 lsB[128 * 32];
  const int tid = threadIdx.x, w = tid >> 6, lane = tid & 63;
  const int l15 = lane & 15, quad = lane >> 4;
  const int m0 = blockIdx.x * 128, n0 = blockIdx.y * 128;
  const int wm = (w >> 1) * 64, wn = (w & 1) * 64;
  const int rowA = lane >> 2;
  const int colk = (lane & 3) * 8;

  f32x4 acc[4][4] = {};

  for (int k0 = 0; k0 < 1024; k0 += 32) {
    __syncthreads();
#pragma unroll
    for (int i = 0; i < 2; i++) {
      int s = w * 2 + i;
      const bf16* ga = A + (size_t)(m0 + s * 16 + rowA) * 1024 + k0 + colk;
      GLOAD_LDS16(ga, lsA + s * 512);
      const bf16* gb = Bt + (size_t)(n0 + s * 16 + rowA) * 1024 + k0 + colk;
      GLOAD_LDS16(gb, lsB + s * 512);
    }
    __syncthreads();

    bf16x8 af[4], bfr[4];
#pragma unroll
    for (int r = 0; r < 4; r++)
      af[r] = *(const bf16x8*)(lsA + (wm + r * 16 + l15) * 32 + quad * 8);
#pragma unroll
    for (int c = 0; c < 4; c++)
      bfr[c] = *(const bf16x8*)(lsB + (wn + c * 16 + l15) * 32 + quad * 8);
#pragma unroll
    for (int r = 0; r < 4; r++)
#pragma unroll
      for (int c = 0; c < 4; c++)
        acc[r][c] = MFMA32(af[r], bfr[c], acc[r][c]);
  }

  if (n0 < 2048) {
#pragma unroll
    for (int r = 0; r < 4; r++) {
#pragma unroll
      for (int c = 0; c < 4; c++) {
        int col = n0 + wn + c * 16 + l15;
        float scale = (col < 1024) ? 0.18033688f : 1.0f;  // 0.125*log2e on Q
#pragma unroll
        for (int e = 0; e < 4; e++) {
          int row = m0 + wm + r * 16 + quad * 4 + e;
          QK[(size_t)row * LDQK + col] = (bf16)(acc[r][c][e] * scale);
        }
      }
    }
  } else {
#pragma unroll
    for (int r = 0; r < 4; r++) {
#pragma unroll
      for (int c = 0; c < 4; c++) {
        int vcol = (n0 - 2048) + wn + c * 16 + l15;
        int row0 = m0 + wm + r * 16 + quad * 4;
        bf16x4 pk;
#pragma unroll
        for (int e = 0; e < 4; e++) pk[e] = (bf16)acc[r][c][e];
        *(bf16x4*)(Vt + (size_t)vcol * S_LEN + row0) = pk;
      }
    }
  }
}

// ----------------------------- flash attention -----------------------------
// 2048 blocks x 256 thr (4 waves). Block i: head=(i&7)+8*((i>>3)&1)
// (XCD-local heads), qb = 127-(i>>4) (LPT; 2x oversubscription -> backfill).
// Block = 32 q-rows [qb*32, +32), 128-key tiles, wave w owns keys w*32..+32
// of each tile. T = qb/4+1. Wave w with w > qb%4 is fully masked on the last
// tile and exits one tile early (no barriers in main loop).
// (256,3): cap 170 combined regs > ~144 need. DO NOT raise to (256,4):
// cap 128 < need -> 506 MB scratch spill, 3.4x slower (round-12 measured).
__global__ __launch_bounds__(256, 3) void flash_attn(const bf16* __restrict__ QK,
                                                     const bf16* __restrict__ Vt,
                                                     bf16* __restrict__ Ctx) {
  __shared__ float Obuf[4][16][68];   // 17.4 KB: per-wave partial O, 16-row chunk
  __shared__ float Lbuf[4][4][32];    // 2 KB
  const int tid = threadIdx.x, w = tid >> 6, lane = tid & 63;
  const int l15 = lane & 15, quad = lane >> 4;
  const int i = blockIdx.x;
  const int head = (i & 7) + 8 * ((i >> 3) & 1);
  const int qb = 127 - (i >> 4);                             // 0..127
  const int hq = head * HDIM;
  const int q0 = qb * 32;
  const int krow0 = w * 32 + ((l15 >> 2) << 3) + (l15 & 3);  // permuted key row
  const int T = (qb >> 2) + 1;                               // 128-key tiles
  // last tile keys for wave w start at (qb/4)*128 + 32w; all-masked iff w > qb%4
  const int Tw = T - ((w > (qb & 3)) ? 1 : 0);

  // Q frags (B-operand): q = q0 + qg*16 + l15, d = kk*32 + quad*8 + j
  bf16x8 qf[2][2];
#pragma unroll
  for (int qg = 0; qg < 2; qg++)
#pragma unroll
    for (int kk = 0; kk < 2; kk++)
      qf[qg][kk] = *(const bf16x8*)(QK + (size_t)(q0 + qg * 16 + l15) * LDQK +
                                    hq + kk * 32 + quad * 8);

  f32x4 oacc[2][4] = {};
  float lsum[2] = {0.f, 0.f};

  auto load_k = [&](int j, bf16x8 (&kf)[2][2]) {
#pragma unroll
    for (int c = 0; c < 2; c++)
#pragma unroll
      for (int kk = 0; kk < 2; kk++)
        kf[c][kk] = *(const bf16x8*)(QK + (size_t)(j * 128 + krow0 + 4 * c) * LDQK +
                                     DMODEL + hq + kk * 32 + quad * 8);
  };
  auto load_v = [&](int j, bf16x8 (&vf)[4]) {
#pragma unroll
    for (int dg = 0; dg < 4; dg++)
      vf[dg] = *(const bf16x8*)(Vt + (size_t)(hq + dg * 16 + l15) * S_LEN +
                                j * 128 + w * 32 + quad * 8);
  };
  auto compute = [&](int j, bf16x8 (&kf)[2][2], bf16x8 (&vf)[4]) {
    __builtin_amdgcn_s_setprio(1);
    // S^T = K Q^T : C row = key-slot quad*4+e (c group), col = q = l15
    f32x4 sacc[2][2] = {};
#pragma unroll
    for (int kk = 0; kk < 2; kk++)
#pragma unroll
      for (int c = 0; c < 2; c++)
#pragma unroll
        for (int qg = 0; qg < 2; qg++)
          sacc[c][qg] = MFMA32(kf[c][kk], qf[qg][kk], sacc[c][qg]);

    bf16x8 pfr[2];
    if (j == T - 1) {
      const int kb0 = j * 128 + w * 32 + quad * 8;   // + 4c + e = actual key
#pragma unroll
      for (int qg = 0; qg < 2; qg++) {
        const int qrow = q0 + qg * 16 + l15;
        bf16x8 pb;
#pragma unroll
        for (int c = 0; c < 2; c++)
#pragma unroll
          for (int e = 0; e < 4; e++) {
            float s = sacc[c][qg][e];
            if (kb0 + 4 * c + e > qrow) s = -1e30f;
            float pv = __builtin_amdgcn_exp2f(s);
            lsum[qg] += pv;
            pb[c * 4 + e] = (bf16)pv;
          }
        pfr[qg] = pb;
      }
    } else {
#pragma unroll
      for (int qg = 0; qg < 2; qg++) {
        bf16x8 pb;
#pragma unroll
        for (int c = 0; c < 2; c++)
#pragma unroll
          for (int e = 0; e < 4; e++) {
            float pv = __builtin_amdgcn_exp2f(sacc[c][qg][e]);
            lsum[qg] += pv;
            pb[c * 4 + e] = (bf16)pv;
          }
        pfr[qg] = pb;
      }
    }

    // O += P V  (K=32, P direct from registers)
#pragma unroll
    for (int qg = 0; qg < 2; qg++)
#pragma unroll
      for (int dg = 0; dg < 4; dg++)
        oacc[qg][dg] = MFMA32(pfr[qg], vf[dg], oacc[qg][dg]);
    __builtin_amdgcn_s_setprio(0);
  };

  // K and V both ping-ponged one tile ahead (R0 pattern).
  bf16x8 kfA[2][2], kfB[2][2], vfA[4], vfB[4];
  if (Tw > 0) {
    load_k(0, kfA); load_v(0, vfA);
    for (int j = 0; j < Tw; j += 2) {
      if (j + 1 < Tw) { load_k(j + 1, kfB); load_v(j + 1, vfB); }
      compute(j, kfA, vfA);
      if (j + 2 < Tw) { load_k(j + 2, kfA); load_v(j + 2, vfA); }
      if (j + 1 < Tw) compute(j + 1, kfB, vfB);
    }
  }

  // ---- cross-wave reduction: all 4 key-split waves share the same 32 rows ----
#pragma unroll
  for (int qg = 0; qg < 2; qg++)
    Lbuf[w][quad][qg * 16 + l15] = lsum[qg];

  const int row = tid >> 4;               // 0..15 (q within 16-row chunk)
  const int col = (tid & 15) * 4;         // 0..60 (d within head)
  for (int cp = 0; cp < 2; cp++) {        // chunk = qg index
#pragma unroll
    for (int dg = 0; dg < 4; dg++)
#pragma unroll
      for (int e = 0; e < 4; e++)
        Obuf[w][quad * 4 + e][dg * 16 + l15] = oacc[cp][dg][e];
    __syncthreads();                      // writes visible (covers Lbuf too)
    f32x4 os = {};
#pragma unroll
    for (int ww = 0; ww < 4; ww++)
      os += *(const f32x4*)&Obuf[ww][row][col];
    float lr = 0.f;
#pragma unroll
    for (int ww = 0; ww < 4; ww++)
#pragma unroll
      for (int qq = 0; qq < 4; qq++)
        lr += Lbuf[ww][qq][cp * 16 + row];
    const float linv = 1.f / lr;
    bf16x4 ob;
#pragma unroll
    for (int e2 = 0; e2 < 4; e2++) ob[e2] = (bf16)(os[e2] * linv);
    *(bf16x4*)(Ctx + (size_t)(q0 + cp * 16 + row) * DMODEL + hq + col) = ob;
    __syncthreads();                      // reads done before next chunk
  }
}

// ---------------- gemm_out: 64x128 tile, K=1024 -> 512 blocks --------------
__global__ __launch_bounds__(256) void gemm_out(const bf16* __restrict__ A,
                                                const bf16* __restrict__ Bt,
                                                float* __restrict__ C,
                                                const float* __restrict__ bias) {
  __shared__ bf16 lsA[64 * 32];
  __shared__ bf16 lsB[128 * 32];
  const int tid = threadIdx.x, w = tid >> 6, lane = tid & 63;
  const int l15 = lane & 15, quad = lane >> 4;
  const int m0 = blockIdx.x * 64, n0 = blockIdx.y * 128;
  const int wm = (w >> 1) * 32, wn = (w & 1) * 64;
  const int rowA = lane >> 2;
  const int colk = (lane & 3) * 8;

  f32x4 acc[2][4] = {};

  for (int k0 = 0; k0 < 1024; k0 += 32) {
    __syncthreads();
#pragma unroll
    for (int i = 0; i < 3; i++) {
      int s = w * 3 + i;
      if (s < 4) {
        const bf16* ga = A + (size_t)(m0 + s * 16 + rowA) * 1024 + k0 + colk;
        GLOAD_LDS16(ga, lsA + s * 512);
      } else {
        const bf16* gb = Bt + (size_t)(n0 + (s - 4) * 16 + rowA) * 1024 + k0 + colk;
        GLOAD_LDS16(gb, lsB + (s - 4) * 512);
      }
    }
    __syncthreads();

    bf16x8 af[2], bfr[4];
#pragma unroll
    for (int r = 0; r < 2; r++)
      af[r] = *(const bf16x8*)(lsA + (wm + r * 16 + l15) * 32 + quad * 8);
#pragma unroll
    for (int c = 0; c < 4; c++)
      bfr[c] = *(const bf16x8*)(lsB + (wn + c * 16 + l15) * 32 + quad * 8);
#pragma unroll
    for (int r = 0; r < 2; r++)
#pragma unroll
      for (int c = 0; c < 4; c++)
        acc[r][c] = MFMA32(af[r], bfr[c], acc[r][c]);
  }

#pragma unroll
  for (int r = 0; r < 2; r++) {
#pragma unroll
    for (int c = 0; c < 4; c++) {
      int col = n0 + wn + c * 16 + l15;
#pragma unroll
      for (int e = 0; e < 4; e++) {
        int row = m0 + wm + r * 16 + quad * 4 + e;
        C[(size_t)row * 1024 + col] = acc[r][c][e] + bias[col];
      }
    }
  }
}

// ------------------------------- launcher ----------------------------------
extern "C" void kernel_launch(void* const* d_in, const int* in_sizes, int n_in,
                              void* d_out, int out_size, void* d_ws, size_t ws_size,
                              hipStream_t stream) {
  const float* x  = (const float*)d_in[0];
  const float* Wq = (const float*)d_in[1];
  const float* Wk = (const float*)d_in[2];
  const float* Wv = (const float*)d_in[3];
  const float* Wo = (const float*)d_in[4];
  const float* bo = (const float*)d_in[5];

  char* ws = (char*)d_ws;                    // 48 MB total
  bf16* xb  = (bf16*)(ws);                   // 8 MB  [4096][1024]
  bf16* Wt  = (bf16*)(ws + (8u  << 20));     // 6 MB  [3072][1024]
  bf16* Wot = (bf16*)(ws + (14u << 20));     // 2 MB  [1024][1024]
  bf16* QK  = (bf16*)(ws + (16u << 20));     // 16 MB [4096][2048]
  bf16* Vt  = (bf16*)(ws + (32u << 20));     // 8 MB  [1024][4096]
  bf16* Ctx = (bf16*)(ws + (40u << 20));     // 8 MB  [4096][1024]

  preprocess<<<2048, 256, 0, stream>>>(x, Wq, Wk, Wv, Wo, xb, Wt, Wot);
  gemm_qkv<<<dim3(32, 24), 256, 0, stream>>>(xb, Wt, QK, Vt);
  flash_attn<<<2048, 256, 0, stream>>>(QK, Vt, Ctx);
  gemm_out<<<dim3(64, 8), 256, 0, stream>>>(Ctx, Wot, (float*)d_out, bo);
}

// Round 5
// 221.271 us; speedup vs baseline: 1.6843x; 1.1762x over previous
//
#include <hip/hip_runtime.h>
#include <hip/hip_bf16.h>
#include <stdint.h>

// ---------------------------------------------------------------------------
// MHA forward, bf16 MFMA path (gfx950).  B=1, S=4096, D=1024, H=16, HD=64.
//   1. preprocess: cast x->bf16 + transpose-cast Wq|Wk|Wv, Wo
//   2. gemm_qkv: QK = xb @ Wt^T (stride 2048, Q pre-scaled 0.125*log2e);
//      V scatter-stored transposed to Vt[1024][4096].  ROUND-14: BK 32->64
//      (m97 structure: 32 MFMA between barriers, half the barrier overhead).
//      Accumulation order unchanged (kk=0 then kk=1 = sequential k) -> bitwise
//      identical results.
//   3. flash_attn: REVERTED VERBATIM to the proven 75-us R0 kernel.
//      Ledger (all measured):
//        R0 64q-wave, K+V pingpong, (256,2): occ 19.5%, 75 us  <- best
//        R1 512-thr paired tiles:            occ 21%,   96 us
//        R2 32q-wave, V just-in-time:        occ 27%,  140 us
//        R3 32q + forced (256,4):            SPILLS (506 MB), 256 us
//        R4 32q + (256,3):                   occ 31.7%, 133 us
//      Conclusion: duration tracks TOTAL CACHE-LINE REQUESTS (R0 8.8M lines
//      = 75us; R2 17M = 140; R4 17.7M = 133), NOT occupancy. 64q waves
//      amortize each K/V line over the most q-rows -> R0 wins. Next lever
//      would be LDS-shared K/V across a 256q block (8-wave restructure).
//   4. gemm_out: out = Ctx @ Wot^T + bo (fp32), 64x128 tiles, BK=64.
// ---------------------------------------------------------------------------

typedef __bf16 bf16;
typedef __bf16 bf16x4 __attribute__((ext_vector_type(4)));
typedef __bf16 bf16x8 __attribute__((ext_vector_type(8)));
typedef float  f32x4  __attribute__((ext_vector_type(4)));

#define MFMA32(a, b, c) __builtin_amdgcn_mfma_f32_16x16x32_bf16((a), (b), (c), 0, 0, 0)

static constexpr int S_LEN  = 4096;
static constexpr int DMODEL = 1024;
static constexpr int HDIM   = 64;
static constexpr int LDQK   = 2048;

#define GLOAD_LDS16(g, l)                                                      \
  __builtin_amdgcn_global_load_lds((__attribute__((address_space(1))) void*)(g), \
                                   (__attribute__((address_space(3))) void*)(l), 16, 0, 0)

// ------------- fused preprocess: cast x + 4 weight transposes --------------
__global__ __launch_bounds__(256) void preprocess(const float* __restrict__ x,
                                                  const float* __restrict__ Wq,
                                                  const float* __restrict__ Wk,
                                                  const float* __restrict__ Wv,
                                                  const float* __restrict__ Wo,
                                                  bf16* __restrict__ xb,
                                                  bf16* __restrict__ Wt,
                                                  bf16* __restrict__ Wot) {
  __shared__ float tile[64][65];
  const int t = threadIdx.x, b = blockIdx.x;
  if (b < 1024) {
#pragma unroll
    for (int i = 0; i < 4; i++) {
      int idx = b * 1024 + i * 256 + t;
      float4 v = ((const float4*)x)[idx];
      bf16x4 o;
      o[0] = (bf16)v.x; o[1] = (bf16)v.y; o[2] = (bf16)v.z; o[3] = (bf16)v.w;
      ((bf16x4*)xb)[idx] = o;
    }
    return;
  }
  const int id = b - 1024;
  const int wsel = id >> 8;
  const int t2 = id & 255;
  const int kb = (t2 & 15) * 64, nb = (t2 >> 4) * 64;
  const float* src = (wsel == 0) ? Wq : (wsel == 1) ? Wk : (wsel == 2) ? Wv : Wo;
  bf16* dst = (wsel < 3) ? (Wt + (size_t)wsel * 1024 * 1024) : Wot;
#pragma unroll
  for (int i = 0; i < 16; i++) {
    int idx = t + i * 256;
    int r = idx >> 6, c = idx & 63;
    tile[r][c] = src[(size_t)(kb + r) * 1024 + nb + c];
  }
  __syncthreads();
#pragma unroll
  for (int i = 0; i < 16; i++) {
    int idx = t + i * 256;
    int cc = idx >> 6, rr = idx & 63;
    dst[(size_t)(nb + cc) * 1024 + kb + rr] = (bf16)tile[rr][cc];
  }
}

// ------------------- gemm_qkv: 128x128 tile, K=1024, BK=64 -----------------
// m97 structure: per K-step each wave stages 4 A-chunks + 4 B-chunks
// (8 rows x 64 k = 1 KB each, global_load_lds width 16) and issues 32 MFMA.
__global__ __launch_bounds__(256) void gemm_qkv(const bf16* __restrict__ A,
                                                const bf16* __restrict__ Bt,
                                                bf16* __restrict__ QK,
                                                bf16* __restrict__ Vt) {
  __shared__ bf16 lsA[128 * 64];
  __shared__ bf16 lsB[128 * 64];
  const int tid = threadIdx.x, w = tid >> 6, lane = tid & 63;
  const int l15 = lane & 15, quad = lane >> 4;
  const int m0 = blockIdx.x * 128, n0 = blockIdx.y * 128;
  const int wm = (w >> 1) * 64, wn = (w & 1) * 64;
  const int rowS = lane >> 3;           // 0..7: row within 8-row chunk
  const int colk = (lane & 7) * 8;      // 0..56: k within 64-k chunk

  f32x4 acc[4][4] = {};

  for (int k0 = 0; k0 < 1024; k0 += 64) {
    __syncthreads();
#pragma unroll
    for (int i = 0; i < 4; i++) {
      int s = w * 4 + i;                // 0..15: 8-row chunk index
      const bf16* ga = A + (size_t)(m0 + s * 8 + rowS) * 1024 + k0 + colk;
      GLOAD_LDS16(ga, lsA + s * 512);
      const bf16* gb = Bt + (size_t)(n0 + s * 8 + rowS) * 1024 + k0 + colk;
      GLOAD_LDS16(gb, lsB + s * 512);
    }
    __syncthreads();

    bf16x8 af[4][2], bfr[4][2];
#pragma unroll
    for (int r = 0; r < 4; r++)
#pragma unroll
      for (int kk = 0; kk < 2; kk++)
        af[r][kk] = *(const bf16x8*)(lsA + (wm + r * 16 + l15) * 64 + kk * 32 + quad * 8);
#pragma unroll
    for (int c = 0; c < 4; c++)
#pragma unroll
      for (int kk = 0; kk < 2; kk++)
        bfr[c][kk] = *(const bf16x8*)(lsB + (wn + c * 16 + l15) * 64 + kk * 32 + quad * 8);
#pragma unroll
    for (int kk = 0; kk < 2; kk++)
#pragma unroll
      for (int r = 0; r < 4; r++)
#pragma unroll
        for (int c = 0; c < 4; c++)
          acc[r][c] = MFMA32(af[r][kk], bfr[c][kk], acc[r][c]);
  }

  if (n0 < 2048) {
#pragma unroll
    for (int r = 0; r < 4; r++) {
#pragma unroll
      for (int c = 0; c < 4; c++) {
        int col = n0 + wn + c * 16 + l15;
        float scale = (col < 1024) ? 0.18033688f : 1.0f;  // 0.125*log2e on Q
#pragma unroll
        for (int e = 0; e < 4; e++) {
          int row = m0 + wm + r * 16 + quad * 4 + e;
          QK[(size_t)row * LDQK + col] = (bf16)(acc[r][c][e] * scale);
        }
      }
    }
  } else {
#pragma unroll
    for (int r = 0; r < 4; r++) {
#pragma unroll
      for (int c = 0; c < 4; c++) {
        int vcol = (n0 - 2048) + wn + c * 16 + l15;
        int row0 = m0 + wm + r * 16 + quad * 4;
        bf16x4 pk;
#pragma unroll
        for (int e = 0; e < 4; e++) pk[e] = (bf16)acc[r][c][e];
        *(bf16x4*)(Vt + (size_t)vcol * S_LEN + row0) = pk;
      }
    }
  }
}

// ----------------------------- flash attention -----------------------------
// VERBATIM R0 (proven 75 us). 1024 blocks, one 64-q tile each; 4 blocks/CU
// comes from the HW VGPR limit (128 VGPR -> 4 waves/EU), NOT launch_bounds.
//   head = (i&7) + 8*((i>>3)&1)   -> each XCD holds only 2 heads' K/V in L2
//   qb   = qt<32 ? qt : 95-qt     -> bijective; per-CU tile-work 67±1
// 128-key tiles, 32 keys/wave; K/V/Q frags global->VGPR, register ping-pong.
__global__ __launch_bounds__(256, 2) void flash_attn(const bf16* __restrict__ QK,
                                                     const bf16* __restrict__ Vt,
                                                     bf16* __restrict__ Ctx) {
  __shared__ float Obuf[4][16][68];   // 17.4 KB: per-wave partial O, one qg chunk
  __shared__ float Lbuf[4][4][64];    // 4 KB
  const int tid = threadIdx.x, w = tid >> 6, lane = tid & 63;
  const int l15 = lane & 15, quad = lane >> 4;
  const int i = blockIdx.x;
  const int head = (i & 7) + 8 * ((i >> 3) & 1);
  const int qt_raw = i >> 4;
  const int qb = (qt_raw < 32) ? qt_raw : (95 - qt_raw);
  const int hq = head * HDIM;
  const int krow0 = w * 32 + ((l15 >> 2) << 3) + (l15 & 3);  // permuted key row

  const int T = (qb >> 1) + 1;              // 128-key tiles

  // Q frags (B-operand): q = qb*64 + qg*16 + l15, d = kk*32 + quad*8 + j
  bf16x8 qf[4][2];
#pragma unroll
  for (int qg = 0; qg < 4; qg++)
#pragma unroll
    for (int kk = 0; kk < 2; kk++)
      qf[qg][kk] = *(const bf16x8*)(QK + (size_t)(qb * 64 + qg * 16 + l15) * LDQK +
                                    hq + kk * 32 + quad * 8);

  f32x4 oacc[4][4] = {};
  float lsum[4] = {0.f, 0.f, 0.f, 0.f};

  auto load_k = [&](int j, bf16x8 (&kf)[2][2]) {
#pragma unroll
    for (int c = 0; c < 2; c++)
#pragma unroll
      for (int kk = 0; kk < 2; kk++)
        kf[c][kk] = *(const bf16x8*)(QK + (size_t)(j * 128 + krow0 + 4 * c) * LDQK +
                                     DMODEL + hq + kk * 32 + quad * 8);
  };
  auto load_v = [&](int j, bf16x8 (&vf)[4]) {
#pragma unroll
    for (int dg = 0; dg < 4; dg++)
      vf[dg] = *(const bf16x8*)(Vt + (size_t)(hq + dg * 16 + l15) * S_LEN +
                                j * 128 + w * 32 + quad * 8);
  };
  auto compute = [&](int j, bf16x8 (&kf)[2][2], bf16x8 (&vf)[4]) {
    // S^T = K Q^T : C row = key-slot quad*4+e (matrix c), col = q = l15
    f32x4 sacc[2][4] = {};
#pragma unroll
    for (int kk = 0; kk < 2; kk++)
#pragma unroll
      for (int c = 0; c < 2; c++)
#pragma unroll
        for (int qg = 0; qg < 4; qg++)
          sacc[c][qg] = MFMA32(kf[c][kk], qf[qg][kk], sacc[c][qg]);

    bf16x8 pfr[4];
    if (j == T - 1) {
      const int kb0 = j * 128 + w * 32 + quad * 8;   // + 4c + e = actual key
#pragma unroll
      for (int qg = 0; qg < 4; qg++) {
        const int qrow = qb * 64 + qg * 16 + l15;
        bf16x8 pb;
#pragma unroll
        for (int c = 0; c < 2; c++)
#pragma unroll
          for (int e = 0; e < 4; e++) {
            float s = sacc[c][qg][e];
            if (kb0 + 4 * c + e > qrow) s = -1e30f;
            float pv = __builtin_amdgcn_exp2f(s);
            lsum[qg] += pv;
            pb[c * 4 + e] = (bf16)pv;
          }
        pfr[qg] = pb;
      }
    } else {
#pragma unroll
      for (int qg = 0; qg < 4; qg++) {
        bf16x8 pb;
#pragma unroll
        for (int c = 0; c < 2; c++)
#pragma unroll
          for (int e = 0; e < 4; e++) {
            float pv = __builtin_amdgcn_exp2f(sacc[c][qg][e]);
            lsum[qg] += pv;
            pb[c * 4 + e] = (bf16)pv;
          }
        pfr[qg] = pb;
      }
    }

    // O += P V  (K=32, P direct from registers)
#pragma unroll
    for (int qg = 0; qg < 4; qg++)
#pragma unroll
      for (int dg = 0; dg < 4; dg++)
        oacc[qg][dg] = MFMA32(pfr[qg], vf[dg], oacc[qg][dg]);
  };

  bf16x8 kfA[2][2], vfA[4], kfB[2][2], vfB[4];
  load_k(0, kfA); load_v(0, vfA);
  for (int j = 0; j < T; j += 2) {
    if (j + 1 < T) { load_k(j + 1, kfB); load_v(j + 1, vfB); }
    compute(j, kfA, vfA);
    if (j + 2 < T) { load_k(j + 2, kfA); load_v(j + 2, vfA); }
    if (j + 1 < T) compute(j + 1, kfB, vfB);
  }

  // ---- chunked cross-wave reduction: one qg (16 q-rows) at a time ----
#pragma unroll
  for (int qg = 0; qg < 4; qg++)
    Lbuf[w][quad][qg * 16 + l15] = lsum[qg];

  const int row = tid >> 4;               // 0..15 (local q within chunk)
  const int col = (tid & 15) * 4;         // 0..60 (d within head)
  for (int qg = 0; qg < 4; qg++) {
#pragma unroll
    for (int dg = 0; dg < 4; dg++)
#pragma unroll
      for (int e = 0; e < 4; e++)
        Obuf[w][quad * 4 + e][dg * 16 + l15] = oacc[qg][dg][e];
    __syncthreads();                      // writes visible
    f32x4 os = {};
#pragma unroll
    for (int ww = 0; ww < 4; ww++)
      os += *(const f32x4*)&Obuf[ww][row][col];
    float lr = 0.f;
#pragma unroll
    for (int ww = 0; ww < 4; ww++)
#pragma unroll
      for (int qq = 0; qq < 4; qq++)
        lr += Lbuf[ww][qq][qg * 16 + row];
    const float linv = 1.f / lr;
    bf16x4 ob;
#pragma unroll
    for (int e2 = 0; e2 < 4; e2++) ob[e2] = (bf16)(os[e2] * linv);
    *(bf16x4*)(Ctx + (size_t)(qb * 64 + qg * 16 + row) * DMODEL + hq + col) = ob;
    __syncthreads();                      // reads done before next chunk
  }
}

// ---------------- gemm_out: 64x128 tile, K=1024, BK=64 ---------------------
__global__ __launch_bounds__(256) void gemm_out(const bf16* __restrict__ A,
                                                const bf16* __restrict__ Bt,
                                                float* __restrict__ C,
                                                const float* __restrict__ bias) {
  __shared__ bf16 lsA[64 * 64];
  __shared__ bf16 lsB[128 * 64];
  const int tid = threadIdx.x, w = tid >> 6, lane = tid & 63;
  const int l15 = lane & 15, quad = lane >> 4;
  const int m0 = blockIdx.x * 64, n0 = blockIdx.y * 128;
  const int wm = (w >> 1) * 32, wn = (w & 1) * 64;
  const int rowS = lane >> 3;           // 0..7
  const int colk = (lane & 7) * 8;      // 0..56

  f32x4 acc[2][4] = {};

  for (int k0 = 0; k0 < 1024; k0 += 64) {
    __syncthreads();
#pragma unroll
    for (int i = 0; i < 6; i++) {
      int s = w * 6 + i;                // 0..23: A chunks 0..7, B chunks 8..23
      if (s < 8) {
        const bf16* ga = A + (size_t)(m0 + s * 8 + rowS) * 1024 + k0 + colk;
        GLOAD_LDS16(ga, lsA + s * 512);
      } else {
        int t = s - 8;
        const bf16* gb = Bt + (size_t)(n0 + t * 8 + rowS) * 1024 + k0 + colk;
        GLOAD_LDS16(gb, lsB + t * 512);
      }
    }
    __syncthreads();

    bf16x8 af[2][2], bfr[4][2];
#pragma unroll
    for (int r = 0; r < 2; r++)
#pragma unroll
      for (int kk = 0; kk < 2; kk++)
        af[r][kk] = *(const bf16x8*)(lsA + (wm + r * 16 + l15) * 64 + kk * 32 + quad * 8);
#pragma unroll
    for (int c = 0; c < 4; c++)
#pragma unroll
      for (int kk = 0; kk < 2; kk++)
        bfr[c][kk] = *(const bf16x8*)(lsB + (wn + c * 16 + l15) * 64 + kk * 32 + quad * 8);
#pragma unroll
    for (int kk = 0; kk < 2; kk++)
#pragma unroll
      for (int r = 0; r < 2; r++)
#pragma unroll
        for (int c = 0; c < 4; c++)
          acc[r][c] = MFMA32(af[r][kk], bfr[c][kk], acc[r][c]);
  }

#pragma unroll
  for (int r = 0; r < 2; r++) {
#pragma unroll
    for (int c = 0; c < 4; c++) {
      int col = n0 + wn + c * 16 + l15;
#pragma unroll
      for (int e = 0; e < 4; e++) {
        int row = m0 + wm + r * 16 + quad * 4 + e;
        C[(size_t)row * 1024 + col] = acc[r][c][e] + bias[col];
      }
    }
  }
}

// ------------------------------- launcher ----------------------------------
extern "C" void kernel_launch(void* const* d_in, const int* in_sizes, int n_in,
                              void* d_out, int out_size, void* d_ws, size_t ws_size,
                              hipStream_t stream) {
  const float* x  = (const float*)d_in[0];
  const float* Wq = (const float*)d_in[1];
  const float* Wk = (const float*)d_in[2];
  const float* Wv = (const float*)d_in[3];
  const float* Wo = (const float*)d_in[4];
  const float* bo = (const float*)d_in[5];

  char* ws = (char*)d_ws;                    // 48 MB total
  bf16* xb  = (bf16*)(ws);                   // 8 MB  [4096][1024]
  bf16* Wt  = (bf16*)(ws + (8u  << 20));     // 6 MB  [3072][1024]
  bf16* Wot = (bf16*)(ws + (14u << 20));     // 2 MB  [1024][1024]
  bf16* QK  = (bf16*)(ws + (16u << 20));     // 16 MB [4096][2048]
  bf16* Vt  = (bf16*)(ws + (32u << 20));     // 8 MB  [1024][4096]
  bf16* Ctx = (bf16*)(ws + (40u << 20));     // 8 MB  [4096][1024]

  preprocess<<<2048, 256, 0, stream>>>(x, Wq, Wk, Wv, Wo, xb, Wt, Wot);
  gemm_qkv<<<dim3(32, 24), 256, 0, stream>>>(xb, Wt, QK, Vt);
  flash_attn<<<1024, 256, 0, stream>>>(QK, Vt, Ctx);
  gemm_out<<<dim3(64, 8), 256, 0, stream>>>(Ctx, Wot, (float*)d_out, bo);
}

// Round 6
// 206.612 us; speedup vs baseline: 1.8038x; 1.0709x over previous
//
#include <hip/hip_runtime.h>
#include <hip/hip_bf16.h>
#include <stdint.h>

// ---------------------------------------------------------------------------
// MHA forward, bf16 MFMA path (gfx950).  B=1, S=4096, D=1024, H=16, HD=64.
//   1. preprocess: cast x->bf16 + transpose-cast Wq|Wk|Wv, Wo
//   2. gemm_qkv: QK = xb @ Wt^T (stride 2048, Q pre-scaled 0.125*log2e);
//      V scatter-stored transposed to Vt[1024][4096].  BK=32 (R15: BK=64
//      regressed -17 us: 128B LDS rows = 16-way ds_read conflict).
//      ROUND-15: both-sides XOR swizzle on the fragment path — linear
//      global_load_lds dest + inverse-swizzled GLOBAL source col-slot
//      ((l&3)^((l>>3)&3)) + swizzled READ slot (quad^((l15>>1)&3)).
//      Kills the baseline 8-way bank conflict (64B row stride, all l15
//      lanes in 2 banks) -> 2 lanes/bank = free (m136). Bit-identical data.
//   3. flash_attn: R0 structure (proven 75 us) + s_setprio(1) around the
//      two MFMA clusters only (m191: +4-7% on barrier-free attn waves;
//      m190's regression case was lockstep-barrier GEMM, not this).
//      Ledger: R0 64q 75us | R1 512thr 96 | R2 32q-JIT-V 140 | R3 spill 256
//      | R4 32q occ31% 133 -> duration tracks cache-line requests, NOT
//      occupancy; 64q waves amortize K/V lines best.
//   4. gemm_out: out = Ctx @ Wot^T + bo (fp32), 64x128 tiles, BK=32,
//      same swizzle.
// ---------------------------------------------------------------------------

typedef __bf16 bf16;
typedef __bf16 bf16x4 __attribute__((ext_vector_type(4)));
typedef __bf16 bf16x8 __attribute__((ext_vector_type(8)));
typedef float  f32x4  __attribute__((ext_vector_type(4)));

#define MFMA32(a, b, c) __builtin_amdgcn_mfma_f32_16x16x32_bf16((a), (b), (c), 0, 0, 0)

static constexpr int S_LEN  = 4096;
static constexpr int DMODEL = 1024;
static constexpr int HDIM   = 64;
static constexpr int LDQK   = 2048;

#define GLOAD_LDS16(g, l)                                                      \
  __builtin_amdgcn_global_load_lds((__attribute__((address_space(1))) void*)(g), \
                                   (__attribute__((address_space(3))) void*)(l), 16, 0, 0)

// ------------- fused preprocess: cast x + 4 weight transposes --------------
__global__ __launch_bounds__(256) void preprocess(const float* __restrict__ x,
                                                  const float* __restrict__ Wq,
                                                  const float* __restrict__ Wk,
                                                  const float* __restrict__ Wv,
                                                  const float* __restrict__ Wo,
                                                  bf16* __restrict__ xb,
                                                  bf16* __restrict__ Wt,
                                                  bf16* __restrict__ Wot) {
  __shared__ float tile[64][65];
  const int t = threadIdx.x, b = blockIdx.x;
  if (b < 1024) {
#pragma unroll
    for (int i = 0; i < 4; i++) {
      int idx = b * 1024 + i * 256 + t;
      float4 v = ((const float4*)x)[idx];
      bf16x4 o;
      o[0] = (bf16)v.x; o[1] = (bf16)v.y; o[2] = (bf16)v.z; o[3] = (bf16)v.w;
      ((bf16x4*)xb)[idx] = o;
    }
    return;
  }
  const int id = b - 1024;
  const int wsel = id >> 8;
  const int t2 = id & 255;
  const int kb = (t2 & 15) * 64, nb = (t2 >> 4) * 64;
  const float* src = (wsel == 0) ? Wq : (wsel == 1) ? Wk : (wsel == 2) ? Wv : Wo;
  bf16* dst = (wsel < 3) ? (Wt + (size_t)wsel * 1024 * 1024) : Wot;
#pragma unroll
  for (int i = 0; i < 16; i++) {
    int idx = t + i * 256;
    int r = idx >> 6, c = idx & 63;
    tile[r][c] = src[(size_t)(kb + r) * 1024 + nb + c];
  }
  __syncthreads();
#pragma unroll
  for (int i = 0; i < 16; i++) {
    int idx = t + i * 256;
    int cc = idx >> 6, rr = idx & 63;
    dst[(size_t)(nb + cc) * 1024 + kb + rr] = (bf16)tile[rr][cc];
  }
}

// ------------------- gemm_qkv: 128x128 tile, K=1024, BK=32 -----------------
// Swizzled fragment path: LDS (row, slot) holds global (row, slot^sigma),
// sigma(row) = (row>>1)&3. Write: linear LDS dest, source col-slot
// (l&3)^((l>>3)&3) (same 64B line -> coalescing unchanged). Read: slot
// quad^((l15>>1)&3) -> 2 lanes/bank (free) instead of 8-way conflict.
__global__ __launch_bounds__(256) void gemm_qkv(const bf16* __restrict__ A,
                                                const bf16* __restrict__ Bt,
                                                bf16* __restrict__ QK,
                                                bf16* __restrict__ Vt) {
  __shared__ bf16 lsA[128 * 32];
  __shared__ bf16 lsB[128 * 32];
  const int tid = threadIdx.x, w = tid >> 6, lane = tid & 63;
  const int l15 = lane & 15, quad = lane >> 4;
  const int m0 = blockIdx.x * 128, n0 = blockIdx.y * 128;
  const int wm = (w >> 1) * 64, wn = (w & 1) * 64;
  const int rowA = lane >> 2;
  const int colk = (((lane & 3) ^ ((lane >> 3) & 3))) * 8;  // inverse-swizzled src
  const int rsl = (l15 >> 1) & 3;                           // read-side swizzle

  f32x4 acc[4][4] = {};

  for (int k0 = 0; k0 < 1024; k0 += 32) {
    __syncthreads();
#pragma unroll
    for (int i = 0; i < 2; i++) {
      int s = w * 2 + i;
      const bf16* ga = A + (size_t)(m0 + s * 16 + rowA) * 1024 + k0 + colk;
      GLOAD_LDS16(ga, lsA + s * 512);
      const bf16* gb = Bt + (size_t)(n0 + s * 16 + rowA) * 1024 + k0 + colk;
      GLOAD_LDS16(gb, lsB + s * 512);
    }
    __syncthreads();

    bf16x8 af[4], bfr[4];
#pragma unroll
    for (int r = 0; r < 4; r++)
      af[r] = *(const bf16x8*)(lsA + (wm + r * 16 + l15) * 32 + (quad ^ rsl) * 8);
#pragma unroll
    for (int c = 0; c < 4; c++)
      bfr[c] = *(const bf16x8*)(lsB + (wn + c * 16 + l15) * 32 + (quad ^ rsl) * 8);
#pragma unroll
    for (int r = 0; r < 4; r++)
#pragma unroll
      for (int c = 0; c < 4; c++)
        acc[r][c] = MFMA32(af[r], bfr[c], acc[r][c]);
  }

  if (n0 < 2048) {
#pragma unroll
    for (int r = 0; r < 4; r++) {
#pragma unroll
      for (int c = 0; c < 4; c++) {
        int col = n0 + wn + c * 16 + l15;
        float scale = (col < 1024) ? 0.18033688f : 1.0f;  // 0.125*log2e on Q
#pragma unroll
        for (int e = 0; e < 4; e++) {
          int row = m0 + wm + r * 16 + quad * 4 + e;
          QK[(size_t)row * LDQK + col] = (bf16)(acc[r][c][e] * scale);
        }
      }
    }
  } else {
#pragma unroll
    for (int r = 0; r < 4; r++) {
#pragma unroll
      for (int c = 0; c < 4; c++) {
        int vcol = (n0 - 2048) + wn + c * 16 + l15;
        int row0 = m0 + wm + r * 16 + quad * 4;
        bf16x4 pk;
#pragma unroll
        for (int e = 0; e < 4; e++) pk[e] = (bf16)acc[r][c][e];
        *(bf16x4*)(Vt + (size_t)vcol * S_LEN + row0) = pk;
      }
    }
  }
}

// ----------------------------- flash attention -----------------------------
// R0 structure (proven 75 us). 1024 blocks, one 64-q tile each; 4 blocks/CU
// comes from the HW VGPR limit (128 VGPR -> 4 waves/EU), NOT launch_bounds.
//   head = (i&7) + 8*((i>>3)&1)   -> each XCD holds only 2 heads' K/V in L2
//   qb   = qt<32 ? qt : 95-qt     -> bijective; per-CU tile-work 67±1
// 128-key tiles, 32 keys/wave; K/V/Q frags global->VGPR, register ping-pong.
// ROUND-15: s_setprio(1) around MFMA clusters only (waves are barrier-free
// and phase-shifted -> the m191 attn case, not the m190 lockstep case).
__global__ __launch_bounds__(256, 2) void flash_attn(const bf16* __restrict__ QK,
                                                     const bf16* __restrict__ Vt,
                                                     bf16* __restrict__ Ctx) {
  __shared__ float Obuf[4][16][68];   // 17.4 KB: per-wave partial O, one qg chunk
  __shared__ float Lbuf[4][4][64];    // 4 KB
  const int tid = threadIdx.x, w = tid >> 6, lane = tid & 63;
  const int l15 = lane & 15, quad = lane >> 4;
  const int i = blockIdx.x;
  const int head = (i & 7) + 8 * ((i >> 3) & 1);
  const int qt_raw = i >> 4;
  const int qb = (qt_raw < 32) ? qt_raw : (95 - qt_raw);
  const int hq = head * HDIM;
  const int krow0 = w * 32 + ((l15 >> 2) << 3) + (l15 & 3);  // permuted key row

  const int T = (qb >> 1) + 1;              // 128-key tiles

  // Q frags (B-operand): q = qb*64 + qg*16 + l15, d = kk*32 + quad*8 + j
  bf16x8 qf[4][2];
#pragma unroll
  for (int qg = 0; qg < 4; qg++)
#pragma unroll
    for (int kk = 0; kk < 2; kk++)
      qf[qg][kk] = *(const bf16x8*)(QK + (size_t)(qb * 64 + qg * 16 + l15) * LDQK +
                                    hq + kk * 32 + quad * 8);

  f32x4 oacc[4][4] = {};
  float lsum[4] = {0.f, 0.f, 0.f, 0.f};

  auto load_k = [&](int j, bf16x8 (&kf)[2][2]) {
#pragma unroll
    for (int c = 0; c < 2; c++)
#pragma unroll
      for (int kk = 0; kk < 2; kk++)
        kf[c][kk] = *(const bf16x8*)(QK + (size_t)(j * 128 + krow0 + 4 * c) * LDQK +
                                     DMODEL + hq + kk * 32 + quad * 8);
  };
  auto load_v = [&](int j, bf16x8 (&vf)[4]) {
#pragma unroll
    for (int dg = 0; dg < 4; dg++)
      vf[dg] = *(const bf16x8*)(Vt + (size_t)(hq + dg * 16 + l15) * S_LEN +
                                j * 128 + w * 32 + quad * 8);
  };
  auto compute = [&](int j, bf16x8 (&kf)[2][2], bf16x8 (&vf)[4]) {
    // S^T = K Q^T : C row = key-slot quad*4+e (matrix c), col = q = l15
    f32x4 sacc[2][4] = {};
    __builtin_amdgcn_s_setprio(1);
#pragma unroll
    for (int kk = 0; kk < 2; kk++)
#pragma unroll
      for (int c = 0; c < 2; c++)
#pragma unroll
        for (int qg = 0; qg < 4; qg++)
          sacc[c][qg] = MFMA32(kf[c][kk], qf[qg][kk], sacc[c][qg]);
    __builtin_amdgcn_s_setprio(0);

    bf16x8 pfr[4];
    if (j == T - 1) {
      const int kb0 = j * 128 + w * 32 + quad * 8;   // + 4c + e = actual key
#pragma unroll
      for (int qg = 0; qg < 4; qg++) {
        const int qrow = qb * 64 + qg * 16 + l15;
        bf16x8 pb;
#pragma unroll
        for (int c = 0; c < 2; c++)
#pragma unroll
          for (int e = 0; e < 4; e++) {
            float s = sacc[c][qg][e];
            if (kb0 + 4 * c + e > qrow) s = -1e30f;
            float pv = __builtin_amdgcn_exp2f(s);
            lsum[qg] += pv;
            pb[c * 4 + e] = (bf16)pv;
          }
        pfr[qg] = pb;
      }
    } else {
#pragma unroll
      for (int qg = 0; qg < 4; qg++) {
        bf16x8 pb;
#pragma unroll
        for (int c = 0; c < 2; c++)
#pragma unroll
          for (int e = 0; e < 4; e++) {
            float pv = __builtin_amdgcn_exp2f(sacc[c][qg][e]);
            lsum[qg] += pv;
            pb[c * 4 + e] = (bf16)pv;
          }
        pfr[qg] = pb;
      }
    }

    // O += P V  (K=32, P direct from registers)
    __builtin_amdgcn_s_setprio(1);
#pragma unroll
    for (int qg = 0; qg < 4; qg++)
#pragma unroll
      for (int dg = 0; dg < 4; dg++)
        oacc[qg][dg] = MFMA32(pfr[qg], vf[dg], oacc[qg][dg]);
    __builtin_amdgcn_s_setprio(0);
  };

  bf16x8 kfA[2][2], vfA[4], kfB[2][2], vfB[4];
  load_k(0, kfA); load_v(0, vfA);
  for (int j = 0; j < T; j += 2) {
    if (j + 1 < T) { load_k(j + 1, kfB); load_v(j + 1, vfB); }
    compute(j, kfA, vfA);
    if (j + 2 < T) { load_k(j + 2, kfA); load_v(j + 2, vfA); }
    if (j + 1 < T) compute(j + 1, kfB, vfB);
  }

  // ---- chunked cross-wave reduction: one qg (16 q-rows) at a time ----
#pragma unroll
  for (int qg = 0; qg < 4; qg++)
    Lbuf[w][quad][qg * 16 + l15] = lsum[qg];

  const int row = tid >> 4;               // 0..15 (local q within chunk)
  const int col = (tid & 15) * 4;         // 0..60 (d within head)
  for (int qg = 0; qg < 4; qg++) {
#pragma unroll
    for (int dg = 0; dg < 4; dg++)
#pragma unroll
      for (int e = 0; e < 4; e++)
        Obuf[w][quad * 4 + e][dg * 16 + l15] = oacc[qg][dg][e];
    __syncthreads();                      // writes visible
    f32x4 os = {};
#pragma unroll
    for (int ww = 0; ww < 4; ww++)
      os += *(const f32x4*)&Obuf[ww][row][col];
    float lr = 0.f;
#pragma unroll
    for (int ww = 0; ww < 4; ww++)
#pragma unroll
      for (int qq = 0; qq < 4; qq++)
        lr += Lbuf[ww][qq][qg * 16 + row];
    const float linv = 1.f / lr;
    bf16x4 ob;
#pragma unroll
    for (int e2 = 0; e2 < 4; e2++) ob[e2] = (bf16)(os[e2] * linv);
    *(bf16x4*)(Ctx + (size_t)(qb * 64 + qg * 16 + row) * DMODEL + hq + col) = ob;
    __syncthreads();                      // reads done before next chunk
  }
}

// ---------------- gemm_out: 64x128 tile, K=1024, BK=32, swizzled -----------
__global__ __launch_bounds__(256) void gemm_out(const bf16* __restrict__ A,
                                                const bf16* __restrict__ Bt,
                                                float* __restrict__ C,
                                                const float* __restrict__ bias) {
  __shared__ bf16 lsA[64 * 32];
  __shared__ bf16 lsB[128 * 32];
  const int tid = threadIdx.x, w = tid >> 6, lane = tid & 63;
  const int l15 = lane & 15, quad = lane >> 4;
  const int m0 = blockIdx.x * 64, n0 = blockIdx.y * 128;
  const int wm = (w >> 1) * 32, wn = (w & 1) * 64;
  const int rowA = lane >> 2;
  const int colk = (((lane & 3) ^ ((lane >> 3) & 3))) * 8;  // inverse-swizzled src
  const int rsl = (l15 >> 1) & 3;                           // read-side swizzle

  f32x4 acc[2][4] = {};

  for (int k0 = 0; k0 < 1024; k0 += 32) {
    __syncthreads();
#pragma unroll
    for (int i = 0; i < 3; i++) {
      int s = w * 3 + i;
      if (s < 4) {
        const bf16* ga = A + (size_t)(m0 + s * 16 + rowA) * 1024 + k0 + colk;
        GLOAD_LDS16(ga, lsA + s * 512);
      } else {
        const bf16* gb = Bt + (size_t)(n0 + (s - 4) * 16 + rowA) * 1024 + k0 + colk;
        GLOAD_LDS16(gb, lsB + (s - 4) * 512);
      }
    }
    __syncthreads();

    bf16x8 af[2], bfr[4];
#pragma unroll
    for (int r = 0; r < 2; r++)
      af[r] = *(const bf16x8*)(lsA + (wm + r * 16 + l15) * 32 + (quad ^ rsl) * 8);
#pragma unroll
    for (int c = 0; c < 4; c++)
      bfr[c] = *(const bf16x8*)(lsB + (wn + c * 16 + l15) * 32 + (quad ^ rsl) * 8);
#pragma unroll
    for (int r = 0; r < 2; r++)
#pragma unroll
      for (int c = 0; c < 4; c++)
        acc[r][c] = MFMA32(af[r], bfr[c], acc[r][c]);
  }

#pragma unroll
  for (int r = 0; r < 2; r++) {
#pragma unroll
    for (int c = 0; c < 4; c++) {
      int col = n0 + wn + c * 16 + l15;
#pragma unroll
      for (int e = 0; e < 4; e++) {
        int row = m0 + wm + r * 16 + quad * 4 + e;
        C[(size_t)row * 1024 + col] = acc[r][c][e] + bias[col];
      }
    }
  }
}

// ------------------------------- launcher ----------------------------------
extern "C" void kernel_launch(void* const* d_in, const int* in_sizes, int n_in,
                              void* d_out, int out_size, void* d_ws, size_t ws_size,
                              hipStream_t stream) {
  const float* x  = (const float*)d_in[0];
  const float* Wq = (const float*)d_in[1];
  const float* Wk = (const float*)d_in[2];
  const float* Wv = (const float*)d_in[3];
  const float* Wo = (const float*)d_in[4];
  const float* bo = (const float*)d_in[5];

  char* ws = (char*)d_ws;                    // 48 MB total
  bf16* xb  = (bf16*)(ws);                   // 8 MB  [4096][1024]
  bf16* Wt  = (bf16*)(ws + (8u  << 20));     // 6 MB  [3072][1024]
  bf16* Wot = (bf16*)(ws + (14u << 20));     // 2 MB  [1024][1024]
  bf16* QK  = (bf16*)(ws + (16u << 20));     // 16 MB [4096][2048]
  bf16* Vt  = (bf16*)(ws + (32u << 20));     // 8 MB  [1024][4096]
  bf16* Ctx = (bf16*)(ws + (40u << 20));     // 8 MB  [4096][1024]

  preprocess<<<2048, 256, 0, stream>>>(x, Wq, Wk, Wv, Wo, xb, Wt, Wot);
  gemm_qkv<<<dim3(32, 24), 256, 0, stream>>>(xb, Wt, QK, Vt);
  flash_attn<<<1024, 256, 0, stream>>>(QK, Vt, Ctx);
  gemm_out<<<dim3(64, 8), 256, 0, stream>>>(Ctx, Wot, (float*)d_out, bo);
}

// Round 7
// 178.240 us; speedup vs baseline: 2.0909x; 1.1592x over previous
//
#include <hip/hip_runtime.h>
#include <hip/hip_bf16.h>
#include <stdint.h>

// ---------------------------------------------------------------------------
// MHA forward, bf16 MFMA path (gfx950).  B=1, S=4096, D=1024, H=16, HD=64.
//   1. preprocess: cast x->bf16 + transpose-cast Wq|Wk|Wv, Wo
//   2. gemm_qkv: Q -> Qb[4096][1024] (pre-scaled 0.125*log2e); K,V written
//      in FRAGMENT-PACKED layouts Kf/Vf (round-16): per (head, 32-key group)
//      a 4KB block holding exactly the bf16x8 chunks flash's waves load, in
//      lane order. Epilogue store offsets are closed-form constants (<8KB).
//   3. flash_attn: R0 structure (64q blocks, K+V register ping-pong).
//      ROUND-16 THEORY: 2730 cyc/tile-wave measured vs ~300 compute ->
//      TA/L2-segment bound (12 frag loads x 16 scattered 64B segments).
//      Packed K/V turn all 12 loads into dense 1KB wave-reads (8x128B
//      lines): segments/tile-wave ~128 -> 48. Ledger: R0 75us | R1 96 |
//      R2 140 | R3 spill 256 | R4 occ-31% 133 -> duration tracks segment
//      count, not occupancy. Swizzle+setprio (R6): neutral on GEMMs/attn.
//   4. gemm_out: out = Ctx @ Wot^T + bo (fp32), 64x128 tiles, BK=32.
// ---------------------------------------------------------------------------

typedef __bf16 bf16;
typedef __bf16 bf16x4 __attribute__((ext_vector_type(4)));
typedef __bf16 bf16x8 __attribute__((ext_vector_type(8)));
typedef float  f32x4  __attribute__((ext_vector_type(4)));

#define MFMA32(a, b, c) __builtin_amdgcn_mfma_f32_16x16x32_bf16((a), (b), (c), 0, 0, 0)

static constexpr int S_LEN  = 4096;
static constexpr int DMODEL = 1024;
static constexpr int HDIM   = 64;

#define GLOAD_LDS16(g, l)                                                      \
  __builtin_amdgcn_global_load_lds((__attribute__((address_space(1))) void*)(g), \
                                   (__attribute__((address_space(3))) void*)(l), 16, 0, 0)

// ------------- fused preprocess: cast x + 4 weight transposes --------------
__global__ __launch_bounds__(256) void preprocess(const float* __restrict__ x,
                                                  const float* __restrict__ Wq,
                                                  const float* __restrict__ Wk,
                                                  const float* __restrict__ Wv,
                                                  const float* __restrict__ Wo,
                                                  bf16* __restrict__ xb,
                                                  bf16* __restrict__ Wt,
                                                  bf16* __restrict__ Wot) {
  __shared__ float tile[64][65];
  const int t = threadIdx.x, b = blockIdx.x;
  if (b < 1024) {
#pragma unroll
    for (int i = 0; i < 4; i++) {
      int idx = b * 1024 + i * 256 + t;
      float4 v = ((const float4*)x)[idx];
      bf16x4 o;
      o[0] = (bf16)v.x; o[1] = (bf16)v.y; o[2] = (bf16)v.z; o[3] = (bf16)v.w;
      ((bf16x4*)xb)[idx] = o;
    }
    return;
  }
  const int id = b - 1024;
  const int wsel = id >> 8;
  const int t2 = id & 255;
  const int kb = (t2 & 15) * 64, nb = (t2 >> 4) * 64;
  const float* src = (wsel == 0) ? Wq : (wsel == 1) ? Wk : (wsel == 2) ? Wv : Wo;
  bf16* dst = (wsel < 3) ? (Wt + (size_t)wsel * 1024 * 1024) : Wot;
#pragma unroll
  for (int i = 0; i < 16; i++) {
    int idx = t + i * 256;
    int r = idx >> 6, c = idx & 63;
    tile[r][c] = src[(size_t)(kb + r) * 1024 + nb + c];
  }
  __syncthreads();
#pragma unroll
  for (int i = 0; i < 16; i++) {
    int idx = t + i * 256;
    int cc = idx >> 6, rr = idx & 63;
    dst[(size_t)(nb + cc) * 1024 + kb + rr] = (bf16)tile[rr][cc];
  }
}

// ------------------- gemm_qkv: 128x128 tile, K=1024, BK=32 -----------------
// Outputs:
//   n0 <  1024 : Qb[row][col] = acc * 0.18033688 (0.125*log2e), stride 1024
//   n0 <  2048 : Kf packed — group g = key>>5 of head h holds 4 chunks
//                (c,kk) of 1KB; lane l=quad*16+l15 chunk offset l*16B holds
//                K[g*32+perm(l15)+4c][h*64+kk*32+quad*8 ..+8],
//                perm(x) = ((x>>2)<<3)|(x&3).
//   else       : Vf packed — group g, 4 chunks dg of 1KB; lane l holds
//                V[h*64+dg*16+l15][g*32+quad*8 ..+8].
// Epilogue maps (r,c,e) -> packed index in closed form (verified algebra,
// see round-16 notes); all (r,c,e) terms are compile-time store offsets.
__global__ __launch_bounds__(256) void gemm_qkv(const bf16* __restrict__ A,
                                                const bf16* __restrict__ Bt,
                                                bf16* __restrict__ Qb,
                                                bf16* __restrict__ Kf,
                                                bf16* __restrict__ Vf) {
  __shared__ bf16 lsA[128 * 32];
  __shared__ bf16 lsB[128 * 32];
  const int tid = threadIdx.x, w = tid >> 6, lane = tid & 63;
  const int l15 = lane & 15, quad = lane >> 4;
  const int m0 = blockIdx.x * 128, n0 = blockIdx.y * 128;
  const int wm = (w >> 1) * 64, wn = (w & 1) * 64;
  const int rowA = lane >> 2;
  const int colk = (((lane & 3) ^ ((lane >> 3) & 3))) * 8;  // inverse-swizzled src
  const int rsl = (l15 >> 1) & 3;                           // read-side swizzle

  f32x4 acc[4][4] = {};

  for (int k0 = 0; k0 < 1024; k0 += 32) {
    __syncthreads();
#pragma unroll
    for (int i = 0; i < 2; i++) {
      int s = w * 2 + i;
      const bf16* ga = A + (size_t)(m0 + s * 16 + rowA) * 1024 + k0 + colk;
      GLOAD_LDS16(ga, lsA + s * 512);
      const bf16* gb = Bt + (size_t)(n0 + s * 16 + rowA) * 1024 + k0 + colk;
      GLOAD_LDS16(gb, lsB + s * 512);
    }
    __syncthreads();

    bf16x8 af[4], bfr[4];
#pragma unroll
    for (int r = 0; r < 4; r++)
      af[r] = *(const bf16x8*)(lsA + (wm + r * 16 + l15) * 32 + (quad ^ rsl) * 8);
#pragma unroll
    for (int c = 0; c < 4; c++)
      bfr[c] = *(const bf16x8*)(lsB + (wn + c * 16 + l15) * 32 + (quad ^ rsl) * 8);
#pragma unroll
    for (int r = 0; r < 4; r++)
#pragma unroll
      for (int c = 0; c < 4; c++)
        acc[r][c] = MFMA32(af[r], bfr[c], acc[r][c]);
  }

  if (n0 < 1024) {
    // ---- Q ----
#pragma unroll
    for (int r = 0; r < 4; r++) {
#pragma unroll
      for (int c = 0; c < 4; c++) {
        int col = n0 + wn + c * 16 + l15;
#pragma unroll
        for (int e = 0; e < 4; e++) {
          int row = m0 + wm + r * 16 + quad * 4 + e;
          Qb[(size_t)row * 1024 + col] = (bf16)(acc[r][c][e] * 0.18033688f);
        }
      }
    }
  } else if (n0 < 2048) {
    // ---- K packed ----
    const int h  = (n0 - 1024 + wn) >> 6;
    const int g0 = (m0 + wm) >> 5;
    bf16* base = Kf + (size_t)(h * 128 + g0) * 2048 +
                 (quad & 1) * 1024 + (l15 >> 3) * 128 + (quad >> 1) * 32 + (l15 & 7);
#pragma unroll
    for (int r = 0; r < 4; r++) {
#pragma unroll
      for (int c = 0; c < 4; c++) {
#pragma unroll
        for (int e = 0; e < 4; e++) {
          base[(r >> 1) * 2048 + (r & 1) * 64 + (c >> 1) * 512 + (c & 1) * 256 + e * 8] =
              (bf16)acc[r][c][e];
        }
      }
    }
  } else {
    // ---- V packed ----
    const int h  = (n0 - 2048 + wn) >> 6;
    const int g0 = (m0 + wm) >> 5;
    bf16* base = Vf + (size_t)(h * 128 + g0) * 2048 +
                 (quad >> 1) * 128 + l15 * 8 + (quad & 1) * 4;
#pragma unroll
    for (int r = 0; r < 4; r++) {
#pragma unroll
      for (int c = 0; c < 4; c++) {
        bf16x4 pk;
#pragma unroll
        for (int e = 0; e < 4; e++) pk[e] = (bf16)acc[r][c][e];
        *(bf16x4*)(base + (r >> 1) * 2048 + (r & 1) * 256 + c * 512) = pk;
      }
    }
  }
}

// ----------------------------- flash attention -----------------------------
// R0 structure (proven 75 us): 1024 blocks, one 64-q tile each, 4 key-split
// waves, K+V register ping-pong, permuted S^T packing, chunked reduction.
//   head = (i&7) + 8*((i>>3)&1)   -> each XCD holds only 2 heads' K/V in L2
//   qb   = qt<32 ? qt : 95-qt     -> bijective; per-CU tile-work 67±1
// ROUND-16: K/V loads from fragment-packed Kf/Vf — every load is a dense
// 1KB wave-read (base + j*8192 + const, lane*16B), no scattered segments.
__global__ __launch_bounds__(256, 2) void flash_attn(const bf16* __restrict__ Qb,
                                                     const bf16* __restrict__ Kf,
                                                     const bf16* __restrict__ Vf,
                                                     bf16* __restrict__ Ctx) {
  __shared__ float Obuf[4][16][68];   // 17.4 KB: per-wave partial O, one qg chunk
  __shared__ float Lbuf[4][4][64];    // 4 KB
  const int tid = threadIdx.x, w = tid >> 6, lane = tid & 63;
  const int l15 = lane & 15, quad = lane >> 4;
  const int i = blockIdx.x;
  const int head = (i & 7) + 8 * ((i >> 3) & 1);
  const int qt_raw = i >> 4;
  const int qb = (qt_raw < 32) ? qt_raw : (95 - qt_raw);
  const int hq = head * HDIM;

  const int T = (qb >> 1) + 1;              // 128-key tiles

  // Packed per-wave base pointers: group g = j*4 + w.
  const bf16* Kw = Kf + (size_t)(head * 128 + w) * 2048 + lane * 8;
  const bf16* Vw = Vf + (size_t)(head * 128 + w) * 2048 + lane * 8;

  // Q frags (B-operand): q = qb*64 + qg*16 + l15, d = kk*32 + quad*8 + j
  bf16x8 qf[4][2];
#pragma unroll
  for (int qg = 0; qg < 4; qg++)
#pragma unroll
    for (int kk = 0; kk < 2; kk++)
      qf[qg][kk] = *(const bf16x8*)(Qb + (size_t)(qb * 64 + qg * 16 + l15) * 1024 +
                                    hq + kk * 32 + quad * 8);

  f32x4 oacc[4][4] = {};
  float lsum[4] = {0.f, 0.f, 0.f, 0.f};

  auto load_k = [&](int j, bf16x8 (&kf)[2][2]) {
#pragma unroll
    for (int c = 0; c < 2; c++)
#pragma unroll
      for (int kk = 0; kk < 2; kk++)
        kf[c][kk] = *(const bf16x8*)(Kw + j * 8192 + c * 1024 + kk * 512);
  };
  auto load_v = [&](int j, bf16x8 (&vf)[4]) {
#pragma unroll
    for (int dg = 0; dg < 4; dg++)
      vf[dg] = *(const bf16x8*)(Vw + j * 8192 + dg * 512);
  };
  auto compute = [&](int j, bf16x8 (&kf)[2][2], bf16x8 (&vf)[4]) {
    // S^T = K Q^T : C row = key-slot quad*4+e (matrix c), col = q = l15
    f32x4 sacc[2][4] = {};
    __builtin_amdgcn_s_setprio(1);
#pragma unroll
    for (int kk = 0; kk < 2; kk++)
#pragma unroll
      for (int c = 0; c < 2; c++)
#pragma unroll
        for (int qg = 0; qg < 4; qg++)
          sacc[c][qg] = MFMA32(kf[c][kk], qf[qg][kk], sacc[c][qg]);
    __builtin_amdgcn_s_setprio(0);

    bf16x8 pfr[4];
    if (j == T - 1) {
      const int kb0 = j * 128 + w * 32 + quad * 8;   // + 4c + e = actual key
#pragma unroll
      for (int qg = 0; qg < 4; qg++) {
        const int qrow = qb * 64 + qg * 16 + l15;
        bf16x8 pb;
#pragma unroll
        for (int c = 0; c < 2; c++)
#pragma unroll
          for (int e = 0; e < 4; e++) {
            float s = sacc[c][qg][e];
            if (kb0 + 4 * c + e > qrow) s = -1e30f;
            float pv = __builtin_amdgcn_exp2f(s);
            lsum[qg] += pv;
            pb[c * 4 + e] = (bf16)pv;
          }
        pfr[qg] = pb;
      }
    } else {
#pragma unroll
      for (int qg = 0; qg < 4; qg++) {
        bf16x8 pb;
#pragma unroll
        for (int c = 0; c < 2; c++)
#pragma unroll
          for (int e = 0; e < 4; e++) {
            float pv = __builtin_amdgcn_exp2f(sacc[c][qg][e]);
            lsum[qg] += pv;
            pb[c * 4 + e] = (bf16)pv;
          }
        pfr[qg] = pb;
      }
    }

    // O += P V  (K=32, P direct from registers)
    __builtin_amdgcn_s_setprio(1);
#pragma unroll
    for (int qg = 0; qg < 4; qg++)
#pragma unroll
      for (int dg = 0; dg < 4; dg++)
        oacc[qg][dg] = MFMA32(pfr[qg], vf[dg], oacc[qg][dg]);
    __builtin_amdgcn_s_setprio(0);
  };

  bf16x8 kfA[2][2], vfA[4], kfB[2][2], vfB[4];
  load_k(0, kfA); load_v(0, vfA);
  for (int j = 0; j < T; j += 2) {
    if (j + 1 < T) { load_k(j + 1, kfB); load_v(j + 1, vfB); }
    compute(j, kfA, vfA);
    if (j + 2 < T) { load_k(j + 2, kfA); load_v(j + 2, vfA); }
    if (j + 1 < T) compute(j + 1, kfB, vfB);
  }

  // ---- chunked cross-wave reduction: one qg (16 q-rows) at a time ----
#pragma unroll
  for (int qg = 0; qg < 4; qg++)
    Lbuf[w][quad][qg * 16 + l15] = lsum[qg];

  const int row = tid >> 4;               // 0..15 (local q within chunk)
  const int col = (tid & 15) * 4;         // 0..60 (d within head)
  for (int qg = 0; qg < 4; qg++) {
#pragma unroll
    for (int dg = 0; dg < 4; dg++)
#pragma unroll
      for (int e = 0; e < 4; e++)
        Obuf[w][quad * 4 + e][dg * 16 + l15] = oacc[qg][dg][e];
    __syncthreads();                      // writes visible
    f32x4 os = {};
#pragma unroll
    for (int ww = 0; ww < 4; ww++)
      os += *(const f32x4*)&Obuf[ww][row][col];
    float lr = 0.f;
#pragma unroll
    for (int ww = 0; ww < 4; ww++)
#pragma unroll
      for (int qq = 0; qq < 4; qq++)
        lr += Lbuf[ww][qq][qg * 16 + row];
    const float linv = 1.f / lr;
    bf16x4 ob;
#pragma unroll
    for (int e2 = 0; e2 < 4; e2++) ob[e2] = (bf16)(os[e2] * linv);
    *(bf16x4*)(Ctx + (size_t)(qb * 64 + qg * 16 + row) * DMODEL + hq + col) = ob;
    __syncthreads();                      // reads done before next chunk
  }
}

// ---------------- gemm_out: 64x128 tile, K=1024, BK=32, swizzled -----------
__global__ __launch_bounds__(256) void gemm_out(const bf16* __restrict__ A,
                                                const bf16* __restrict__ Bt,
                                                float* __restrict__ C,
                                                const float* __restrict__ bias) {
  __shared__ bf16 lsA[64 * 32];
  __shared__ bf16 lsB[128 * 32];
  const int tid = threadIdx.x, w = tid >> 6, lane = tid & 63;
  const int l15 = lane & 15, quad = lane >> 4;
  const int m0 = blockIdx.x * 64, n0 = blockIdx.y * 128;
  const int wm = (w >> 1) * 32, wn = (w & 1) * 64;
  const int rowA = lane >> 2;
  const int colk = (((lane & 3) ^ ((lane >> 3) & 3))) * 8;  // inverse-swizzled src
  const int rsl = (l15 >> 1) & 3;                           // read-side swizzle

  f32x4 acc[2][4] = {};

  for (int k0 = 0; k0 < 1024; k0 += 32) {
    __syncthreads();
#pragma unroll
    for (int i = 0; i < 3; i++) {
      int s = w * 3 + i;
      if (s < 4) {
        const bf16* ga = A + (size_t)(m0 + s * 16 + rowA) * 1024 + k0 + colk;
        GLOAD_LDS16(ga, lsA + s * 512);
      } else {
        const bf16* gb = Bt + (size_t)(n0 + (s - 4) * 16 + rowA) * 1024 + k0 + colk;
        GLOAD_LDS16(gb, lsB + (s - 4) * 512);
      }
    }
    __syncthreads();

    bf16x8 af[2], bfr[4];
#pragma unroll
    for (int r = 0; r < 2; r++)
      af[r] = *(const bf16x8*)(lsA + (wm + r * 16 + l15) * 32 + (quad ^ rsl) * 8);
#pragma unroll
    for (int c = 0; c < 4; c++)
      bfr[c] = *(const bf16x8*)(lsB + (wn + c * 16 + l15) * 32 + (quad ^ rsl) * 8);
#pragma unroll
    for (int r = 0; r < 2; r++)
#pragma unroll
      for (int c = 0; c < 4; c++)
        acc[r][c] = MFMA32(af[r], bfr[c], acc[r][c]);
  }

#pragma unroll
  for (int r = 0; r < 2; r++) {
#pragma unroll
    for (int c = 0; c < 4; c++) {
      int col = n0 + wn + c * 16 + l15;
#pragma unroll
      for (int e = 0; e < 4; e++) {
        int row = m0 + wm + r * 16 + quad * 4 + e;
        C[(size_t)row * 1024 + col] = acc[r][c][e] + bias[col];
      }
    }
  }
}

// ------------------------------- launcher ----------------------------------
extern "C" void kernel_launch(void* const* d_in, const int* in_sizes, int n_in,
                              void* d_out, int out_size, void* d_ws, size_t ws_size,
                              hipStream_t stream) {
  const float* x  = (const float*)d_in[0];
  const float* Wq = (const float*)d_in[1];
  const float* Wk = (const float*)d_in[2];
  const float* Wv = (const float*)d_in[3];
  const float* Wo = (const float*)d_in[4];
  const float* bo = (const float*)d_in[5];

  char* ws = (char*)d_ws;                    // 48 MB total
  bf16* xb  = (bf16*)(ws);                   // 8 MB  [4096][1024]
  bf16* Wt  = (bf16*)(ws + (8u  << 20));     // 6 MB  [3072][1024]
  bf16* Wot = (bf16*)(ws + (14u << 20));     // 2 MB  [1024][1024]
  bf16* Qb  = (bf16*)(ws + (16u << 20));     // 8 MB  [4096][1024]
  bf16* Kf  = (bf16*)(ws + (24u << 20));     // 8 MB  packed K frags
  bf16* Vf  = (bf16*)(ws + (32u << 20));     // 8 MB  packed V frags
  bf16* Ctx = (bf16*)(ws + (40u << 20));     // 8 MB  [4096][1024]

  preprocess<<<2048, 256, 0, stream>>>(x, Wq, Wk, Wv, Wo, xb, Wt, Wot);
  gemm_qkv<<<dim3(32, 24), 256, 0, stream>>>(xb, Wt, Qb, Kf, Vf);
  flash_attn<<<1024, 256, 0, stream>>>(Qb, Kf, Vf, Ctx);
  gemm_out<<<dim3(64, 8), 256, 0, stream>>>(Ctx, Wot, (float*)d_out, bo);
}